// Round 1
// baseline (2171.332 us; speedup 1.0000x reference)
//
#include <hip/hip_runtime.h>

// DCGRU cell, MI355X gfx950.  N=4096, B=64, IN_DIM=2, UNITS=64, K=2, NSUP=2,
// M=5, IN_SZ=66.  Heavy: 8x GEMM Y(4096x4224)=S(4096x4096)@X, bf16 MFMA.
// GEMM is the m201-style 256x256x64 8-phase template: st_16x32 LDS swizzle
// (inverse-swizzled global_load_lds source + swizzled ds_read), counted
// vmcnt(6) at K-tile boundaries only, raw s_barrier, setprio around MFMA.
// N padded 4224->4352 (17 col tiles); pad cols are quarantined (valid rows
// depend only on valid B rows).  g2+g3 fused via blockIdx.z (share B=y1T).

typedef unsigned short u16;
typedef unsigned int u32;
typedef __attribute__((ext_vector_type(8))) short short8;   // bf16x8 MFMA frag
typedef __attribute__((ext_vector_type(4))) float floatx4;  // MFMA acc
typedef __attribute__((ext_vector_type(4))) u16 u16x4;

__device__ __forceinline__ u16 f2b(float f) {            // fp32 -> bf16 RNE
    u32 x = __float_as_uint(f);
    return (u16)((x + 0x7fffu + ((x >> 16) & 1u)) >> 16);
}
__device__ __forceinline__ float b2f(u16 u) {
    return __uint_as_float(((u32)u) << 16);
}

// async global->LDS, 16B per lane; LDS dest = wave-uniform base + lane*16
#define GLL16(g, l) __builtin_amdgcn_global_load_lds( \
    (const __attribute__((address_space(1))) void*)(g), \
    (__attribute__((address_space(3))) void*)(l), 16, 0, 0)

// ---------------------------------------------------------------- cvt fp32->bf16
__global__ void cvt_bf16_kernel(const float* __restrict__ src, u16* __restrict__ dst) {
    size_t i = ((size_t)blockIdx.x * 256 + threadIdx.x) * 4;
    floatx4 v = *(const floatx4*)&src[i];
    u16x4 p; p[0] = f2b(v[0]); p[1] = f2b(v[1]); p[2] = f2b(v[2]); p[3] = f2b(v[3]);
    *(u16x4*)&dst[i] = p;
}

// ------------------------------------------- x0T rows 0..127  (c=0,1 from inputs)
__global__ void build_x0_inputs(const float* __restrict__ inp, u16* __restrict__ x0T) {
    const int row = blockIdx.x;           // 0..127
    const int c = row >> 6, b = row & 63;
    const int t = threadIdx.x;
    const int n0 = t * 16;
    u16* dst = x0T + (size_t)row * 4096 + n0;
    #pragma unroll
    for (int g = 0; g < 4; ++g) {
        u16x4 pk;
        #pragma unroll
        for (int e = 0; e < 4; ++e) {
            const float* p = &inp[(size_t)b * 8192 + (size_t)(n0 + g * 4 + e) * 2];
            pk[e] = f2b(c ? p[1] : p[0]);
        }
        *(u16x4*)(dst + g * 4) = pk;
    }
}

// ----------------------------- x0T rows 128..4223 from state (hx):  transpose
__global__ void build_x0_state(const float* __restrict__ st, u16* __restrict__ x0T) {
    __shared__ float lds[64 * 68];
    const int t = threadIdx.x;
    const int n0 = blockIdx.x * 64, b = blockIdx.y;
    const float* src = st + (size_t)b * 262144 + (size_t)n0 * 64;
    #pragma unroll
    for (int r = 0; r < 4; ++r) {
        int i = r * 1024 + t * 4;
        floatx4 v = *(const floatx4*)&src[i];
        int nl = i >> 6, j = i & 63;
        *(floatx4*)&lds[nl * 68 + j] = v;
    }
    __syncthreads();
    const int j = t >> 2, q = t & 3;
    u16* dst = x0T + (size_t)((j + 2) * 64 + b) * 4096 + n0 + q * 16;
    #pragma unroll
    for (int g = 0; g < 4; ++g) {
        u16x4 pk;
        #pragma unroll
        for (int e = 0; e < 4; ++e) pk[e] = f2b(lds[(q * 16 + g * 4 + e) * 68 + j]);
        *(u16x4*)(dst + g * 4) = pk;
    }
}

// -------------------------------------------- W^T prep: WT[o][k] bf16, k pad 384
__global__ void wt_prep(const float* __restrict__ W, u16* __restrict__ WT, int O) {
    int idx = blockIdx.x * 256 + threadIdx.x;   // o*384 + k
    int o = idx / 384, k = idx - o * 384;
    if (o < O) WT[idx] = (k < 330) ? f2b(W[(size_t)k * O + o]) : (u16)0;
}

// --------------------------------------------------------------- bf16 MFMA GEMM
// 256x256 tile, BK=64, 8 waves (2M x 4N), per-wave 128x64 output (one 64x64
// block in each M-half / N-half).  C[m][col] = sum_k A[m][k]*B[col][k];
// store YT[col][m].  If Z != null: Y = 2*C - Z.  blockIdx.z selects arg set
// (fusing two independent GEMMs sharing B).
// LDS map (128KB): base(buf,ab,half) = buf*65536 + ab*32768 + half*16384,
// each half = [128 rows][64 k] bf16 row-major, st_16x32 swizzle
// byte ^= ((byte>>9)&1)<<5 applied on read AND inverse-applied on the
// global source of global_load_lds (linear LDS dest, rule #21).
// Schedule per K-tile t (buf = t&1): 4 phases.
//  ph1: ds-read A-h0(8) + B-h0(4)  | stage B1(t+1)->buf^1 | MFMA M0N0
//  ph2: ds-read B-h1(4)            | stage A0(t+2)->buf   | MFMA M0N1
//  ph3: ds-read A-h1(8)            | stage B0(t+2)->buf   | MFMA M1N0
//  ph4: (regs only)                | stage A1(t+2)->buf   | MFMA M1N1, vmcnt(6)
// vmcnt(6) = 3 newest half-tiles (A0,B0,A1 of t+2) may stay in flight; the
// oldest pending (B1(t+1)) is forced complete -> K-tile t+1 fully resident.
// Every overwrite of an LDS region is >=1 closing barrier after its last read.
__global__ __launch_bounds__(512, 2) void gemm256_kernel(
        const u16* __restrict__ Aa, const u16* __restrict__ Ab,
        const u16* __restrict__ B,
        u16* __restrict__ Ya, u16* __restrict__ Yb,
        const u16* __restrict__ Za, const u16* __restrict__ Zb) {
    __shared__ __align__(128) char sm[131072];
    const u16* A = blockIdx.z ? Ab : Aa;
    u16*       Y = blockIdx.z ? Yb : Ya;
    const u16* Z = blockIdx.z ? Zb : Za;
    const int t = threadIdx.x;
    const int lane = t & 63, wave = t >> 6;
    const int m16 = lane & 15, quad = lane >> 4;
    const int wr = wave >> 2, wc = wave & 3;     // 2M x 4N waves
    const int rb = blockIdx.x, cb = blockIdx.y;

    // ---- staging source (per-lane, inverse-swizzled); LDS dest stays linear.
    // element idx within a [128][64] half: (q*4096 + wave*512 + lane*8) ^ (lane>=32 ? 16 : 0)
    const int swe = (lane & 32) ? 16 : 0;
    const int idx0 = ((wave * 512 + lane * 8) ^ swe);
    const int idx1 = ((4096 + wave * 512 + lane * 8) ^ swe);
    const size_t off0 = (size_t)(idx0 >> 6) * 4096 + (idx0 & 63);
    const size_t off1 = (size_t)(idx1 >> 6) * 4096 + (idx1 & 63);
    const u16* aS0 = A + (size_t)rb * (256 * 4096) + off0;
    const u16* aS1 = A + (size_t)rb * (256 * 4096) + off1;
    const u16* bS0 = B + (size_t)cb * (256 * 4096) + off0;
    const u16* bS1 = B + (size_t)cb * (256 * 4096) + off1;
    const int ldsW = wave * 1024;                // wave-uniform GLL dest base

    // ---- ds-read bases, swizzle folded in (bit9 of addr == row&4 == m16&4)
    const int swb = (m16 & 4) ? 32 : 0;
    const int aRd = (((wr * 64 + m16) * 128 + quad * 16) ^ swb);
    const int bRd = 32768 + (((wc * 32 + m16) * 128 + quad * 16) ^ swb);

    floatx4 acc[8][4];
    #pragma unroll
    for (int i = 0; i < 8; ++i)
        #pragma unroll
        for (int j = 0; j < 4; ++j) acc[i][j] = (floatx4)0.f;

    // ---- prologue: K0 -> buf0 (A0,B0,A1,B1) + K1 -> buf1 (A0,B0,A1) = 14 loads
    GLL16(aS0,               sm + (0     + ldsW));
    GLL16(aS1,               sm + (8192  + ldsW));
    GLL16(bS0,               sm + (32768 + ldsW));
    GLL16(bS1,               sm + (40960 + ldsW));
    GLL16(aS0 + 524288,      sm + (16384 + ldsW));
    GLL16(aS1 + 524288,      sm + (24576 + ldsW));
    GLL16(bS0 + 524288,      sm + (49152 + ldsW));
    GLL16(bS1 + 524288,      sm + (57344 + ldsW));
    GLL16(aS0 + 64,          sm + (65536 + 0     + ldsW));
    GLL16(aS1 + 64,          sm + (65536 + 8192  + ldsW));
    GLL16(bS0 + 64,          sm + (65536 + 32768 + ldsW));
    GLL16(bS1 + 64,          sm + (65536 + 40960 + ldsW));
    GLL16(aS0 + 524288 + 64, sm + (65536 + 16384 + ldsW));
    GLL16(aS1 + 524288 + 64, sm + (65536 + 24576 + ldsW));
    asm volatile("s_waitcnt vmcnt(6)" ::: "memory");   // K0 resident, 3 halves in flight
    __builtin_amdgcn_s_barrier();

    for (int tt = 0; tt < 64; ++tt) {
        const int bb  = (tt & 1) << 16;
        const int ob  = bb ^ 65536;
        const int to1 = ((tt + 1) & 63) << 6;   // k elem offset, wraps (garbage quarantined)
        const int to2 = ((tt + 2) & 63) << 6;
        short8 a0[4][2], a1[4][2], b0[2][2], b1[2][2];

        // ---------------- phase 1: read A-h0 + B-h0 ; stage B1(t+1) -> other buf
        #pragma unroll
        for (int i = 0; i < 4; ++i)
            #pragma unroll
            for (int k = 0; k < 2; ++k)
                a0[i][k] = *(const short8*)(sm + (bb + aRd + i * 2048 + k * 64));
        #pragma unroll
        for (int j = 0; j < 2; ++j)
            #pragma unroll
            for (int k = 0; k < 2; ++k)
                b0[j][k] = *(const short8*)(sm + (bb + bRd + j * 2048 + k * 64));
        GLL16(bS0 + 524288 + to1, sm + (ob + 49152 + ldsW));
        GLL16(bS1 + 524288 + to1, sm + (ob + 57344 + ldsW));
        __builtin_amdgcn_s_barrier();
        asm volatile("s_waitcnt lgkmcnt(0)" ::: "memory");
        __builtin_amdgcn_sched_barrier(0);
        __builtin_amdgcn_s_setprio(1);
        #pragma unroll
        for (int i = 0; i < 4; ++i)
            #pragma unroll
            for (int j = 0; j < 2; ++j)
                #pragma unroll
                for (int k = 0; k < 2; ++k)
                    acc[i][j] = __builtin_amdgcn_mfma_f32_16x16x32_bf16(a0[i][k], b0[j][k], acc[i][j], 0, 0, 0);
        __builtin_amdgcn_s_setprio(0);
        __builtin_amdgcn_s_barrier();

        // ---------------- phase 2: read B-h1 ; stage A0(t+2) -> this buf
        #pragma unroll
        for (int j = 0; j < 2; ++j)
            #pragma unroll
            for (int k = 0; k < 2; ++k)
                b1[j][k] = *(const short8*)(sm + (bb + bRd + 16384 + j * 2048 + k * 64));
        GLL16(aS0 + to2, sm + (bb + 0    + ldsW));
        GLL16(aS1 + to2, sm + (bb + 8192 + ldsW));
        __builtin_amdgcn_s_barrier();
        asm volatile("s_waitcnt lgkmcnt(0)" ::: "memory");
        __builtin_amdgcn_sched_barrier(0);
        __builtin_amdgcn_s_setprio(1);
        #pragma unroll
        for (int i = 0; i < 4; ++i)
            #pragma unroll
            for (int j = 0; j < 2; ++j)
                #pragma unroll
                for (int k = 0; k < 2; ++k)
                    acc[i][2 + j] = __builtin_amdgcn_mfma_f32_16x16x32_bf16(a0[i][k], b1[j][k], acc[i][2 + j], 0, 0, 0);
        __builtin_amdgcn_s_setprio(0);
        __builtin_amdgcn_s_barrier();

        // ---------------- phase 3: read A-h1 ; stage B0(t+2) -> this buf
        #pragma unroll
        for (int i = 0; i < 4; ++i)
            #pragma unroll
            for (int k = 0; k < 2; ++k)
                a1[i][k] = *(const short8*)(sm + (bb + aRd + 16384 + i * 2048 + k * 64));
        GLL16(bS0 + to2, sm + (bb + 32768 + ldsW));
        GLL16(bS1 + to2, sm + (bb + 40960 + ldsW));
        __builtin_amdgcn_s_barrier();
        asm volatile("s_waitcnt lgkmcnt(0)" ::: "memory");
        __builtin_amdgcn_sched_barrier(0);
        __builtin_amdgcn_s_setprio(1);
        #pragma unroll
        for (int i = 0; i < 4; ++i)
            #pragma unroll
            for (int j = 0; j < 2; ++j)
                #pragma unroll
                for (int k = 0; k < 2; ++k)
                    acc[4 + i][j] = __builtin_amdgcn_mfma_f32_16x16x32_bf16(a1[i][k], b0[j][k], acc[4 + i][j], 0, 0, 0);
        __builtin_amdgcn_s_setprio(0);
        __builtin_amdgcn_s_barrier();

        // ---------------- phase 4: regs only ; stage A1(t+2) ; counted vmcnt
        GLL16(aS0 + 524288 + to2, sm + (bb + 16384 + ldsW));
        GLL16(aS1 + 524288 + to2, sm + (bb + 24576 + ldsW));
        __builtin_amdgcn_s_barrier();
        __builtin_amdgcn_s_setprio(1);
        #pragma unroll
        for (int i = 0; i < 4; ++i)
            #pragma unroll
            for (int j = 0; j < 2; ++j)
                #pragma unroll
                for (int k = 0; k < 2; ++k)
                    acc[4 + i][2 + j] = __builtin_amdgcn_mfma_f32_16x16x32_bf16(a1[i][k], b1[j][k], acc[4 + i][2 + j], 0, 0, 0);
        __builtin_amdgcn_s_setprio(0);
        asm volatile("s_waitcnt vmcnt(6)" ::: "memory");   // next K-tile resident
        __builtin_amdgcn_s_barrier();
    }

    // ---------------- epilogue: C (+ optional 2*C - Z) -> YT[col][row] bf16
    #pragma unroll
    for (int i = 0; i < 8; ++i) {
        const int row = rb * 256 + (i >> 2) * 128 + wr * 64 + (i & 3) * 16 + quad * 4;
        #pragma unroll
        for (int j = 0; j < 4; ++j) {
            const int col = cb * 256 + (j >> 1) * 128 + wc * 32 + (j & 1) * 16 + m16;
            const size_t off = (size_t)col * 4096 + row;
            floatx4 v = acc[i][j];
            if (Z) {
                u16x4 zz = *(const u16x4*)(Z + off);
                #pragma unroll
                for (int e = 0; e < 4; ++e) v[e] = 2.f * v[e] - b2f(zz[e]);
            }
            u16x4 pk;
            #pragma unroll
            for (int e = 0; e < 4; ++e) pk[e] = f2b(v[e]);
            *(u16x4*)(Y + off) = pk;
        }
    }
}

// --------------------------------------------------------- proj helpers (X rows)
__device__ __forceinline__ const u16* xrow(int k, int b,
        const u16* x0, const u16* y1, const u16* y2, const u16* y3, const u16* y4) {
    int c = (int)((unsigned)k / 5u);
    int m = k - c * 5;
    if (c > 65) c = 65;                       // pad region: clamp in-bounds (W=0 there)
    const u16* base = (m == 0) ? x0 : (m == 1) ? y1 : (m == 2) ? y2 : (m == 3) ? y3 : y4;
    return base + (size_t)(c * 64 + b) * 4096;
}

__device__ __forceinline__ void ilv(uint4 a, uint4 b, u32* w) {
    // a = 8 bf16 of row k, b = 8 bf16 of row k+1 -> 8 words (k|k+1<<16) per bn
    const u32* ap = (const u32*)&a; const u32* bp = (const u32*)&b;
    #pragma unroll
    for (int i = 0; i < 4; ++i) {
        u32 x = ap[i], y = bp[i];
        w[2 * i]     = (x & 0xffffu) | (y << 16);
        w[2 * i + 1] = (x >> 16) | (y & 0xffff0000u);
    }
}

// ------------------------------------------------- proj fn: MFMA GEMM + gates
__global__ __launch_bounds__(256, 2) void proj_fn_kernel(
        const u16* __restrict__ x0T, const u16* __restrict__ y1T,
        const u16* __restrict__ y2T, const u16* __restrict__ y3T,
        const u16* __restrict__ y4T,
        const u16* __restrict__ WT, const float* __restrict__ bias,
        const float* __restrict__ hx,
        u16* __restrict__ u_t, u16* __restrict__ x0Tw) {
    __shared__ __align__(16) u32 Xs[32 * 132];   // [kp][bn] interleaved, 16.9 KB
    __shared__ __align__(16) u16 Ws[128 * 72];   // [o][k] pad 72, 18.4 KB
    const int t = threadIdx.x;
    const int lane = t & 63, wave = t >> 6;
    const int m16 = lane & 15, quad = lane >> 4;
    const int wr = wave >> 1, wc = wave & 1;
    const int n0 = blockIdx.x * 128, b = blockIdx.y;

    const int kp = t >> 3, sgx = t & 7;          // X staging: kp 0..31, 16 n per sgx
    const int wrow = t >> 1, whalf = t & 1;      // W staging

    floatx4 acc[4][4];
    #pragma unroll
    for (int i = 0; i < 4; ++i)
        #pragma unroll
        for (int j = 0; j < 4; ++j) acc[i][j] = (floatx4)0.f;

    for (int ki = 0; ki < 6; ++ki) {
        const int k0 = ki * 64;
        const u16* pa = xrow(k0 + 2 * kp,     b, x0T, y1T, y2T, y3T, y4T) + n0 + sgx * 16;
        const u16* pb = xrow(k0 + 2 * kp + 1, b, x0T, y1T, y2T, y3T, y4T) + n0 + sgx * 16;
        uint4 a0 = *(const uint4*)pa;
        uint4 a1 = *(const uint4*)(pa + 8);
        uint4 b0 = *(const uint4*)pb;
        uint4 b1 = *(const uint4*)(pb + 8);
        const u16* wsrc = WT + (size_t)wrow * 384 + k0 + whalf * 32;
        uint4 wv[4];
        #pragma unroll
        for (int q = 0; q < 4; ++q) wv[q] = *(const uint4*)(wsrc + q * 8);

        u32 w[16];
        ilv(a0, b0, w);
        ilv(a1, b1, w + 8);
        __syncthreads();                          // prev tile reads done
        u32* xdst = &Xs[kp * 132 + sgx * 16];
        #pragma unroll
        for (int q = 0; q < 4; ++q) *(uint4*)(xdst + q * 4) = *(uint4*)(w + q * 4);
        uint4* wdst = (uint4*)&Ws[wrow * 72 + whalf * 32];
        #pragma unroll
        for (int q = 0; q < 4; ++q) wdst[q] = wv[q];
        __syncthreads();

        #pragma unroll
        for (int ks = 0; ks < 2; ++ks) {
            short8 af[4], bf[4];
            #pragma unroll
            for (int i = 0; i < 4; ++i)
                af[i] = *(const short8*)&Ws[(wr * 64 + i * 16 + m16) * 72 + ks * 32 + quad * 8];
            #pragma unroll
            for (int j = 0; j < 4; ++j) {
                const u32* xp = &Xs[(ks * 16 + quad * 4) * 132 + wc * 64 + j * 16 + m16];
                union { uint4 u; short8 s; } fu;
                fu.u.x = xp[0]; fu.u.y = xp[132]; fu.u.z = xp[264]; fu.u.w = xp[396];
                bf[j] = fu.s;
            }
            #pragma unroll
            for (int i = 0; i < 4; ++i)
                #pragma unroll
                for (int j = 0; j < 4; ++j)
                    acc[i][j] = __builtin_amdgcn_mfma_f32_16x16x32_bf16(af[i], bf[j], acc[i][j], 0, 0, 0);
        }
    }
    // epilogue
    #pragma unroll
    for (int i = 0; i < 4; ++i) {
        const int o0 = wr * 64 + i * 16 + quad * 4;
        floatx4 bz = *(const floatx4*)&bias[o0];
        #pragma unroll
        for (int j = 0; j < 4; ++j) {
            const int bnl = wc * 64 + j * 16 + m16;
            const size_t bn = (size_t)b * 4096 + n0 + bnl;
            floatx4 v = acc[i][j];
            float s[4];
            #pragma unroll
            for (int e = 0; e < 4; ++e) s[e] = 1.f / (1.f + __expf(-(v[e] + bz[e])));
            if (wr == 0) {          // r -> x0T state rows: bf16(r*hx)
                floatx4 hv = *(const floatx4*)&hx[bn * 64 + o0];
                #pragma unroll
                for (int e = 0; e < 4; ++e)
                    x0Tw[(size_t)((o0 + e + 2) * 64 + b) * 4096 + (n0 + bnl)] = f2b(s[e] * hv[e]);
            } else {                // u -> u_t[bn][o-64]
                u16x4 pk;
                #pragma unroll
                for (int e = 0; e < 4; ++e) pk[e] = f2b(s[e]);
                *(u16x4*)&u_t[bn * 64 + (o0 - 64)] = pk;
            }
        }
    }
}

// --------------------------------------- proj g: MFMA GEMM + tanh + GRU output
__global__ __launch_bounds__(256, 2) void proj_g_kernel(
        const u16* __restrict__ x0T, const u16* __restrict__ y1T,
        const u16* __restrict__ y2T, const u16* __restrict__ y3T,
        const u16* __restrict__ y4T,
        const u16* __restrict__ WT, const float* __restrict__ bias,
        const float* __restrict__ hx, const u16* __restrict__ u_t,
        float* __restrict__ out) {
    __shared__ __align__(16) u32 Xs[32 * 132];
    __shared__ __align__(16) u16 Ws[64 * 72];
    const int t = threadIdx.x;
    const int lane = t & 63, wave = t >> 6;
    const int m16 = lane & 15, quad = lane >> 4;
    const int wr = wave >> 1, wc = wave & 1;
    const int n0 = blockIdx.x * 128, b = blockIdx.y;

    const int kp = t >> 3, sgx = t & 7;
    const int wrow = t >> 2, wq = t & 3;

    floatx4 acc[2][4];
    #pragma unroll
    for (int i = 0; i < 2; ++i)
        #pragma unroll
        for (int j = 0; j < 4; ++j) acc[i][j] = (floatx4)0.f;

    for (int ki = 0; ki < 6; ++ki) {
        const int k0 = ki * 64;
        const u16* pa = xrow(k0 + 2 * kp,     b, x0T, y1T, y2T, y3T, y4T) + n0 + sgx * 16;
        const u16* pb = xrow(k0 + 2 * kp + 1, b, x0T, y1T, y2T, y3T, y4T) + n0 + sgx * 16;
        uint4 a0 = *(const uint4*)pa;
        uint4 a1 = *(const uint4*)(pa + 8);
        uint4 b0 = *(const uint4*)pb;
        uint4 b1 = *(const uint4*)(pb + 8);
        const u16* wsrc = WT + (size_t)wrow * 384 + k0 + wq * 16;
        uint4 w0 = *(const uint4*)wsrc;
        uint4 w1 = *(const uint4*)(wsrc + 8);

        u32 w[16];
        ilv(a0, b0, w);
        ilv(a1, b1, w + 8);
        __syncthreads();
        u32* xdst = &Xs[kp * 132 + sgx * 16];
        #pragma unroll
        for (int q = 0; q < 4; ++q) *(uint4*)(xdst + q * 4) = *(uint4*)(w + q * 4);
        *(uint4*)&Ws[wrow * 72 + wq * 16] = w0;
        *(uint4*)&Ws[wrow * 72 + wq * 16 + 8] = w1;
        __syncthreads();

        #pragma unroll
        for (int ks = 0; ks < 2; ++ks) {
            short8 af[2], bf[4];
            #pragma unroll
            for (int i = 0; i < 2; ++i)
                af[i] = *(const short8*)&Ws[(wr * 32 + i * 16 + m16) * 72 + ks * 32 + quad * 8];
            #pragma unroll
            for (int j = 0; j < 4; ++j) {
                const u32* xp = &Xs[(ks * 16 + quad * 4) * 132 + wc * 64 + j * 16 + m16];
                union { uint4 u; short8 s; } fu;
                fu.u.x = xp[0]; fu.u.y = xp[132]; fu.u.z = xp[264]; fu.u.w = xp[396];
                bf[j] = fu.s;
            }
            #pragma unroll
            for (int i = 0; i < 2; ++i)
                #pragma unroll
                for (int j = 0; j < 4; ++j)
                    acc[i][j] = __builtin_amdgcn_mfma_f32_16x16x32_bf16(af[i], bf[j], acc[i][j], 0, 0, 0);
        }
    }
    #pragma unroll
    for (int i = 0; i < 2; ++i) {
        const int o0 = wr * 32 + i * 16 + quad * 4;
        floatx4 bz = *(const floatx4*)&bias[o0];
        #pragma unroll
        for (int j = 0; j < 4; ++j) {
            const int bnl = wc * 64 + j * 16 + m16;
            const size_t bn = (size_t)b * 4096 + n0 + bnl;
            floatx4 v = acc[i][j];
            u16x4 uu = *(const u16x4*)&u_t[bn * 64 + o0];
            floatx4 hv = *(const floatx4*)&hx[bn * 64 + o0];
            floatx4 ov;
            #pragma unroll
            for (int e = 0; e < 4; ++e) {
                float c = tanhf(v[e] + bz[e]);
                float u = b2f(uu[e]);
                ov[e] = u * hv[e] + (1.f - u) * c;
            }
            *(floatx4*)&out[bn * 64 + o0] = ov;
        }
    }
}

// --------------------------------------------------------------------- launch
extern "C" void kernel_launch(void* const* d_in, const int* in_sizes, int n_in,
                              void* d_out, int out_size, void* d_ws, size_t ws_size,
                              hipStream_t stream) {
    (void)in_sizes; (void)n_in; (void)out_size; (void)ws_size;
    const float* inputs   = (const float*)d_in[0];
    const float* hx       = (const float*)d_in[1];
    const float* supports = (const float*)d_in[2];
    const float* w_fn     = (const float*)d_in[3];
    const float* b_fn     = (const float*)d_in[4];
    const float* w_g      = (const float*)d_in[5];
    const float* b_g      = (const float*)d_in[6];
    float* out = (float*)d_out;

    const size_t NN  = (size_t)4096 * 4096;
    const size_t XTP = (size_t)4352 * 4096;     // padded to 17 col-tiles of 256
    u16* Sb  = (u16*)d_ws;                      // 67.1 MB
    u16* x0T = Sb + 2 * NN;                     // 35.7 MB each (padded)
    u16* y1T = x0T + XTP;
    u16* y2T = y1T + XTP;
    u16* y3T = y2T + XTP;
    u16* y4T = y3T + XTP;
    u16* u_t = y4T + XTP;                       // [bn][o'] bf16, 33.6 MB
    u16* WT_fn = u_t + (size_t)262144 * 64;     // 128*384 u16
    u16* WT_g  = WT_fn + 128 * 384;             // 64*384 u16
    u16* S0b = Sb;
    u16* S1b = Sb + NN;

    const dim3 g1(16, 17, 1);                   // single GEMM
    const dim3 g2(16, 17, 2);                   // fused pair (shared B)

    cvt_bf16_kernel<<<32768, 256, 0, stream>>>(supports, Sb);
    build_x0_inputs<<<128, 256, 0, stream>>>(inputs, x0T);
    build_x0_state<<<dim3(64, 64), 256, 0, stream>>>(hx, x0T);
    wt_prep<<<192, 256, 0, stream>>>(w_fn, WT_fn, 128);
    wt_prep<<<96, 256, 0, stream>>>(w_g, WT_g, 64);
    // gconv fn diffusion: y1 = S0@x0; {y2 = 2*S0@y1 - x0, y3 = S1@y1}; y4 = 2*S1@y3 - y1
    gemm256_kernel<<<g1, 512, 0, stream>>>(S0b, nullptr, x0T, y1T, nullptr, nullptr, nullptr);
    gemm256_kernel<<<g2, 512, 0, stream>>>(S0b, S1b, y1T, y2T, y3T, x0T, nullptr);
    gemm256_kernel<<<g1, 512, 0, stream>>>(S1b, nullptr, y3T, y4T, nullptr, y1T, nullptr);
    // r,u gates (MFMA): r*hx into x0T state rows, u into u_t
    proj_fn_kernel<<<dim3(32, 64), 256, 0, stream>>>(x0T, y1T, y2T, y3T, y4T,
                                                     WT_fn, b_fn, hx, u_t, x0T);
    // gconv g diffusion
    gemm256_kernel<<<g1, 512, 0, stream>>>(S0b, nullptr, x0T, y1T, nullptr, nullptr, nullptr);
    gemm256_kernel<<<g2, 512, 0, stream>>>(S0b, S1b, y1T, y2T, y3T, x0T, nullptr);
    gemm256_kernel<<<g1, 512, 0, stream>>>(S1b, nullptr, y3T, y4T, nullptr, y1T, nullptr);
    // c = tanh(...), out = u*hx + (1-u)*c
    proj_g_kernel<<<dim3(32, 64), 256, 0, stream>>>(x0T, y1T, y2T, y3T, y4T,
                                                    WT_g, b_g, hx, u_t, out);
}

// Round 2
// 1973.688 us; speedup vs baseline: 1.1001x; 1.1001x over previous
//
#include <hip/hip_runtime.h>

// DCGRU cell, MI355X gfx950.  N=4096, B=64, IN_DIM=2, UNITS=64, K=2, NSUP=2,
// M=5, IN_SZ=66.  Heavy: 8x GEMM Y(4096x4224)=S(4096x4096)@X, bf16 MFMA.
// GEMM is the m201-style 256x256x64 8-phase template with the FULL 3-bit
// stripe swizzle (byte ^= (row&7)<<4): inverse-swizzled global_load_lds
// source (lane' = lane ^ (lane>>3)) + swizzled ds_read, counted vmcnt(6)
// at K-tile boundaries only, raw s_barrier, setprio around MFMA.
// N padded 4224->4352 (17 col tiles); pad cols quarantined.
// g2+g3 fused via blockIdx.z (share B=y1T).

typedef unsigned short u16;
typedef unsigned int u32;
typedef __attribute__((ext_vector_type(8))) short short8;   // bf16x8 MFMA frag
typedef __attribute__((ext_vector_type(4))) float floatx4;  // MFMA acc
typedef __attribute__((ext_vector_type(4))) u16 u16x4;

__device__ __forceinline__ u16 f2b(float f) {            // fp32 -> bf16 RNE
    u32 x = __float_as_uint(f);
    return (u16)((x + 0x7fffu + ((x >> 16) & 1u)) >> 16);
}
__device__ __forceinline__ float b2f(u16 u) {
    return __uint_as_float(((u32)u) << 16);
}

// async global->LDS, 16B per lane; LDS dest = wave-uniform base + lane*16
#define GLL16(g, l) __builtin_amdgcn_global_load_lds( \
    (const __attribute__((address_space(1))) void*)(g), \
    (__attribute__((address_space(3))) void*)(l), 16, 0, 0)

// ---------------------------------------------------------------- cvt fp32->bf16
__global__ void cvt_bf16_kernel(const float* __restrict__ src, u16* __restrict__ dst) {
    size_t i = ((size_t)blockIdx.x * 256 + threadIdx.x) * 4;
    floatx4 v = *(const floatx4*)&src[i];
    u16x4 p; p[0] = f2b(v[0]); p[1] = f2b(v[1]); p[2] = f2b(v[2]); p[3] = f2b(v[3]);
    *(u16x4*)&dst[i] = p;
}

// ------------------------------------------- x0T rows 0..127  (c=0,1 from inputs)
__global__ void build_x0_inputs(const float* __restrict__ inp, u16* __restrict__ x0T) {
    const int row = blockIdx.x;           // 0..127
    const int c = row >> 6, b = row & 63;
    const int t = threadIdx.x;
    const int n0 = t * 16;
    u16* dst = x0T + (size_t)row * 4096 + n0;
    #pragma unroll
    for (int g = 0; g < 4; ++g) {
        u16x4 pk;
        #pragma unroll
        for (int e = 0; e < 4; ++e) {
            const float* p = &inp[(size_t)b * 8192 + (size_t)(n0 + g * 4 + e) * 2];
            pk[e] = f2b(c ? p[1] : p[0]);
        }
        *(u16x4*)(dst + g * 4) = pk;
    }
}

// ----------------------------- x0T rows 128..4223 from state (hx):  transpose
__global__ void build_x0_state(const float* __restrict__ st, u16* __restrict__ x0T) {
    __shared__ float lds[64 * 68];
    const int t = threadIdx.x;
    const int n0 = blockIdx.x * 64, b = blockIdx.y;
    const float* src = st + (size_t)b * 262144 + (size_t)n0 * 64;
    #pragma unroll
    for (int r = 0; r < 4; ++r) {
        int i = r * 1024 + t * 4;
        floatx4 v = *(const floatx4*)&src[i];
        int nl = i >> 6, j = i & 63;
        *(floatx4*)&lds[nl * 68 + j] = v;
    }
    __syncthreads();
    const int j = t >> 2, q = t & 3;
    u16* dst = x0T + (size_t)((j + 2) * 64 + b) * 4096 + n0 + q * 16;
    #pragma unroll
    for (int g = 0; g < 4; ++g) {
        u16x4 pk;
        #pragma unroll
        for (int e = 0; e < 4; ++e) pk[e] = f2b(lds[(q * 16 + g * 4 + e) * 68 + j]);
        *(u16x4*)(dst + g * 4) = pk;
    }
}

// -------------------------------------------- W^T prep: WT[o][k] bf16, k pad 384
__global__ void wt_prep(const float* __restrict__ W, u16* __restrict__ WT, int O) {
    int idx = blockIdx.x * 256 + threadIdx.x;   // o*384 + k
    int o = idx / 384, k = idx - o * 384;
    if (o < O) WT[idx] = (k < 330) ? f2b(W[(size_t)k * O + o]) : (u16)0;
}

// --------------------------------------------------------------- bf16 MFMA GEMM
// 256x256 tile, BK=64, 8 waves (2M x 4N), per-wave 128x64 output (one 64x64
// block in each M-half / N-half).  C[m][col] = sum_k A[m][k]*B[col][k];
// store YT[col][m].  If Z != null: Y = 2*C - Z.  blockIdx.z selects arg set
// (fusing two independent GEMMs sharing B).
// LDS map (128KB): base(buf,ab,half) = buf*65536 + ab*32768 + half*16384,
// each half = [128 rows][64 k] bf16 row-major (128B rows).
// Swizzle (3-bit stripe, G4/T2): byte_off ^= ((row&7)<<4).  Applied on the
// ds_read address; inverse-applied on the global SOURCE of global_load_lds
// (linear LDS dest, rule #21): dest elem e needs logical elem
// e ^ (((e>>6)&7)<<3)  ->  per-lane source lane' = lane ^ (lane>>3).
// Schedule per K-tile t (buf = t&1): 4 phases.
//  ph1: ds-read A-h0(8) + B-h0(4)  | stage B1(t+1)->buf^1 | MFMA M0N0
//  ph2: ds-read B-h1(4)            | stage A0(t+2)->buf   | MFMA M0N1
//  ph3: ds-read A-h1(8)            | stage B0(t+2)->buf   | MFMA M1N0
//  ph4: (regs only)                | stage A1(t+2)->buf   | MFMA M1N1, vmcnt(6)
// vmcnt(6) = 3 newest half-tiles (A0,B0,A1 of t+2) may stay in flight; the
// oldest pending (B1(t+1)) is forced complete -> K-tile t+1 fully resident.
__global__ __launch_bounds__(512, 2) void gemm256_kernel(
        const u16* __restrict__ Aa, const u16* __restrict__ Ab,
        const u16* __restrict__ B,
        u16* __restrict__ Ya, u16* __restrict__ Yb,
        const u16* __restrict__ Za, const u16* __restrict__ Zb) {
    __shared__ __align__(128) char sm[131072];
    const u16* A = blockIdx.z ? Ab : Aa;
    u16*       Y = blockIdx.z ? Yb : Ya;
    const u16* Z = blockIdx.z ? Zb : Za;
    const int t = threadIdx.x;
    const int lane = t & 63, wave = t >> 6;
    const int m16 = lane & 15, quad = lane >> 4;
    const int wr = wave >> 2, wc = wave & 3;     // 2M x 4N waves
    const int rb = blockIdx.x, cb = blockIdx.y;

    // ---- staging source (per-lane, inverse-swizzled); LDS dest stays linear.
    // element idx within a [128][64] half: wave*512 + (lane ^ (lane>>3))*8
    const int lp = (lane ^ (lane >> 3));
    const int idx0 = wave * 512 + lp * 8;
    const int idx1 = 4096 + idx0;
    const size_t off0 = (size_t)(idx0 >> 6) * 4096 + (idx0 & 63);
    const size_t off1 = (size_t)(idx1 >> 6) * 4096 + (idx1 & 63);
    const u16* aS0 = A + (size_t)rb * (256 * 4096) + off0;
    const u16* aS1 = A + (size_t)rb * (256 * 4096) + off1;
    const u16* bS0 = B + (size_t)cb * (256 * 4096) + off0;
    const u16* bS1 = B + (size_t)cb * (256 * 4096) + off1;
    const int ldsW = wave * 1024;                // wave-uniform GLL dest base

    // ---- ds-read bases: rowbase (bits>=7, swizzle-invariant) + swizzled col.
    // col(k) = (quad*16 + k*64) ^ ((m16&7)<<4); k*64 folded by XOR (bit 6).
    const int swb = (m16 & 7) << 4;
    const int cSw = (quad * 16) ^ swb;           // k=0 column; k=1 is cSw^64
    const int aRd = (wr * 64 + m16) * 128;
    const int bRd = 32768 + (wc * 32 + m16) * 128;

    floatx4 acc[8][4];
    #pragma unroll
    for (int i = 0; i < 8; ++i)
        #pragma unroll
        for (int j = 0; j < 4; ++j) acc[i][j] = (floatx4)0.f;

    // ---- prologue: K0 -> buf0 (A0,B0,A1,B1) + K1 -> buf1 (A0,B0,A1) = 14 loads
    GLL16(aS0,               sm + (0     + ldsW));
    GLL16(aS1,               sm + (8192  + ldsW));
    GLL16(bS0,               sm + (32768 + ldsW));
    GLL16(bS1,               sm + (40960 + ldsW));
    GLL16(aS0 + 524288,      sm + (16384 + ldsW));
    GLL16(aS1 + 524288,      sm + (24576 + ldsW));
    GLL16(bS0 + 524288,      sm + (49152 + ldsW));
    GLL16(bS1 + 524288,      sm + (57344 + ldsW));
    GLL16(aS0 + 64,          sm + (65536 + 0     + ldsW));
    GLL16(aS1 + 64,          sm + (65536 + 8192  + ldsW));
    GLL16(bS0 + 64,          sm + (65536 + 32768 + ldsW));
    GLL16(bS1 + 64,          sm + (65536 + 40960 + ldsW));
    GLL16(aS0 + 524288 + 64, sm + (65536 + 16384 + ldsW));
    GLL16(aS1 + 524288 + 64, sm + (65536 + 24576 + ldsW));
    asm volatile("s_waitcnt vmcnt(6)" ::: "memory");   // K0 resident, 3 halves in flight
    __builtin_amdgcn_s_barrier();

    for (int tt = 0; tt < 64; ++tt) {
        const int bb  = (tt & 1) << 16;
        const int ob  = bb ^ 65536;
        const int to1 = ((tt + 1) & 63) << 6;   // k elem offset, wraps (garbage quarantined)
        const int to2 = ((tt + 2) & 63) << 6;
        short8 a0[4][2], a1[4][2], b0[2][2], b1[2][2];

        // ---------------- phase 1: read A-h0 + B-h0 ; stage B1(t+1) -> other buf
        #pragma unroll
        for (int i = 0; i < 4; ++i)
            #pragma unroll
            for (int k = 0; k < 2; ++k)
                a0[i][k] = *(const short8*)(sm + (bb + aRd + i * 2048 + (cSw ^ (k << 6))));
        #pragma unroll
        for (int j = 0; j < 2; ++j)
            #pragma unroll
            for (int k = 0; k < 2; ++k)
                b0[j][k] = *(const short8*)(sm + (bb + bRd + j * 2048 + (cSw ^ (k << 6))));
        GLL16(bS0 + 524288 + to1, sm + (ob + 49152 + ldsW));
        GLL16(bS1 + 524288 + to1, sm + (ob + 57344 + ldsW));
        __builtin_amdgcn_s_barrier();
        asm volatile("s_waitcnt lgkmcnt(0)" ::: "memory");
        __builtin_amdgcn_sched_barrier(0);
        __builtin_amdgcn_s_setprio(1);
        #pragma unroll
        for (int i = 0; i < 4; ++i)
            #pragma unroll
            for (int j = 0; j < 2; ++j)
                #pragma unroll
                for (int k = 0; k < 2; ++k)
                    acc[i][j] = __builtin_amdgcn_mfma_f32_16x16x32_bf16(a0[i][k], b0[j][k], acc[i][j], 0, 0, 0);
        __builtin_amdgcn_s_setprio(0);
        __builtin_amdgcn_s_barrier();

        // ---------------- phase 2: read B-h1 ; stage A0(t+2) -> this buf
        #pragma unroll
        for (int j = 0; j < 2; ++j)
            #pragma unroll
            for (int k = 0; k < 2; ++k)
                b1[j][k] = *(const short8*)(sm + (bb + bRd + 16384 + j * 2048 + (cSw ^ (k << 6))));
        GLL16(aS0 + to2, sm + (bb + 0    + ldsW));
        GLL16(aS1 + to2, sm + (bb + 8192 + ldsW));
        __builtin_amdgcn_s_barrier();
        asm volatile("s_waitcnt lgkmcnt(0)" ::: "memory");
        __builtin_amdgcn_sched_barrier(0);
        __builtin_amdgcn_s_setprio(1);
        #pragma unroll
        for (int i = 0; i < 4; ++i)
            #pragma unroll
            for (int j = 0; j < 2; ++j)
                #pragma unroll
                for (int k = 0; k < 2; ++k)
                    acc[i][2 + j] = __builtin_amdgcn_mfma_f32_16x16x32_bf16(a0[i][k], b1[j][k], acc[i][2 + j], 0, 0, 0);
        __builtin_amdgcn_s_setprio(0);
        __builtin_amdgcn_s_barrier();

        // ---------------- phase 3: read A-h1 ; stage B0(t+2) -> this buf
        #pragma unroll
        for (int i = 0; i < 4; ++i)
            #pragma unroll
            for (int k = 0; k < 2; ++k)
                a1[i][k] = *(const short8*)(sm + (bb + aRd + 16384 + i * 2048 + (cSw ^ (k << 6))));
        GLL16(bS0 + to2, sm + (bb + 32768 + ldsW));
        GLL16(bS1 + to2, sm + (bb + 40960 + ldsW));
        __builtin_amdgcn_s_barrier();
        asm volatile("s_waitcnt lgkmcnt(0)" ::: "memory");
        __builtin_amdgcn_sched_barrier(0);
        __builtin_amdgcn_s_setprio(1);
        #pragma unroll
        for (int i = 0; i < 4; ++i)
            #pragma unroll
            for (int j = 0; j < 2; ++j)
                #pragma unroll
                for (int k = 0; k < 2; ++k)
                    acc[4 + i][j] = __builtin_amdgcn_mfma_f32_16x16x32_bf16(a1[i][k], b0[j][k], acc[4 + i][j], 0, 0, 0);
        __builtin_amdgcn_s_setprio(0);
        __builtin_amdgcn_s_barrier();

        // ---------------- phase 4: regs only ; stage A1(t+2) ; counted vmcnt
        GLL16(aS0 + 524288 + to2, sm + (bb + 16384 + ldsW));
        GLL16(aS1 + 524288 + to2, sm + (bb + 24576 + ldsW));
        __builtin_amdgcn_s_barrier();
        __builtin_amdgcn_s_setprio(1);
        #pragma unroll
        for (int i = 0; i < 4; ++i)
            #pragma unroll
            for (int j = 0; j < 2; ++j)
                #pragma unroll
                for (int k = 0; k < 2; ++k)
                    acc[4 + i][2 + j] = __builtin_amdgcn_mfma_f32_16x16x32_bf16(a1[i][k], b1[j][k], acc[4 + i][2 + j], 0, 0, 0);
        __builtin_amdgcn_s_setprio(0);
        asm volatile("s_waitcnt vmcnt(6)" ::: "memory");   // next K-tile resident
        __builtin_amdgcn_s_barrier();
    }

    // ---------------- epilogue: C (+ optional 2*C - Z) -> YT[col][row] bf16
    #pragma unroll
    for (int i = 0; i < 8; ++i) {
        const int row = rb * 256 + (i >> 2) * 128 + wr * 64 + (i & 3) * 16 + quad * 4;
        #pragma unroll
        for (int j = 0; j < 4; ++j) {
            const int col = cb * 256 + (j >> 1) * 128 + wc * 32 + (j & 1) * 16 + m16;
            const size_t off = (size_t)col * 4096 + row;
            floatx4 v = acc[i][j];
            if (Z) {
                u16x4 zz = *(const u16x4*)(Z + off);
                #pragma unroll
                for (int e = 0; e < 4; ++e) v[e] = 2.f * v[e] - b2f(zz[e]);
            }
            u16x4 pk;
            #pragma unroll
            for (int e = 0; e < 4; ++e) pk[e] = f2b(v[e]);
            *(u16x4*)(Y + off) = pk;
        }
    }
}

// --------------------------------------------------------- proj helpers (X rows)
__device__ __forceinline__ const u16* xrow(int k, int b,
        const u16* x0, const u16* y1, const u16* y2, const u16* y3, const u16* y4) {
    int c = (int)((unsigned)k / 5u);
    int m = k - c * 5;
    if (c > 65) c = 65;                       // pad region: clamp in-bounds (W=0 there)
    const u16* base = (m == 0) ? x0 : (m == 1) ? y1 : (m == 2) ? y2 : (m == 3) ? y3 : y4;
    return base + (size_t)(c * 64 + b) * 4096;
}

__device__ __forceinline__ void ilv(uint4 a, uint4 b, u32* w) {
    // a = 8 bf16 of row k, b = 8 bf16 of row k+1 -> 8 words (k|k+1<<16) per bn
    const u32* ap = (const u32*)&a; const u32* bp = (const u32*)&b;
    #pragma unroll
    for (int i = 0; i < 4; ++i) {
        u32 x = ap[i], y = bp[i];
        w[2 * i]     = (x & 0xffffu) | (y << 16);
        w[2 * i + 1] = (x >> 16) | (y & 0xffff0000u);
    }
}

// ------------------------------------------------- proj fn: MFMA GEMM + gates
__global__ __launch_bounds__(256, 2) void proj_fn_kernel(
        const u16* __restrict__ x0T, const u16* __restrict__ y1T,
        const u16* __restrict__ y2T, const u16* __restrict__ y3T,
        const u16* __restrict__ y4T,
        const u16* __restrict__ WT, const float* __restrict__ bias,
        const float* __restrict__ hx,
        u16* __restrict__ u_t, u16* __restrict__ x0Tw) {
    __shared__ __align__(16) u32 Xs[32 * 132];   // [kp][bn] interleaved, 16.9 KB
    __shared__ __align__(16) u16 Ws[128 * 72];   // [o][k] pad 72, 18.4 KB
    const int t = threadIdx.x;
    const int lane = t & 63, wave = t >> 6;
    const int m16 = lane & 15, quad = lane >> 4;
    const int wr = wave >> 1, wc = wave & 1;
    const int n0 = blockIdx.x * 128, b = blockIdx.y;

    const int kp = t >> 3, sgx = t & 7;          // X staging: kp 0..31, 16 n per sgx
    const int wrow = t >> 1, whalf = t & 1;      // W staging

    floatx4 acc[4][4];
    #pragma unroll
    for (int i = 0; i < 4; ++i)
        #pragma unroll
        for (int j = 0; j < 4; ++j) acc[i][j] = (floatx4)0.f;

    for (int ki = 0; ki < 6; ++ki) {
        const int k0 = ki * 64;
        const u16* pa = xrow(k0 + 2 * kp,     b, x0T, y1T, y2T, y3T, y4T) + n0 + sgx * 16;
        const u16* pb = xrow(k0 + 2 * kp + 1, b, x0T, y1T, y2T, y3T, y4T) + n0 + sgx * 16;
        uint4 a0 = *(const uint4*)pa;
        uint4 a1 = *(const uint4*)(pa + 8);
        uint4 b0 = *(const uint4*)pb;
        uint4 b1 = *(const uint4*)(pb + 8);
        const u16* wsrc = WT + (size_t)wrow * 384 + k0 + whalf * 32;
        uint4 wv[4];
        #pragma unroll
        for (int q = 0; q < 4; ++q) wv[q] = *(const uint4*)(wsrc + q * 8);

        u32 w[16];
        ilv(a0, b0, w);
        ilv(a1, b1, w + 8);
        __syncthreads();                          // prev tile reads done
        u32* xdst = &Xs[kp * 132 + sgx * 16];
        #pragma unroll
        for (int q = 0; q < 4; ++q) *(uint4*)(xdst + q * 4) = *(uint4*)(w + q * 4);
        uint4* wdst = (uint4*)&Ws[wrow * 72 + whalf * 32];
        #pragma unroll
        for (int q = 0; q < 4; ++q) wdst[q] = wv[q];
        __syncthreads();

        #pragma unroll
        for (int ks = 0; ks < 2; ++ks) {
            short8 af[4], bf[4];
            #pragma unroll
            for (int i = 0; i < 4; ++i)
                af[i] = *(const short8*)&Ws[(wr * 64 + i * 16 + m16) * 72 + ks * 32 + quad * 8];
            #pragma unroll
            for (int j = 0; j < 4; ++j) {
                const u32* xp = &Xs[(ks * 16 + quad * 4) * 132 + wc * 64 + j * 16 + m16];
                union { uint4 u; short8 s; } fu;
                fu.u.x = xp[0]; fu.u.y = xp[132]; fu.u.z = xp[264]; fu.u.w = xp[396];
                bf[j] = fu.s;
            }
            #pragma unroll
            for (int i = 0; i < 4; ++i)
                #pragma unroll
                for (int j = 0; j < 4; ++j)
                    acc[i][j] = __builtin_amdgcn_mfma_f32_16x16x32_bf16(af[i], bf[j], acc[i][j], 0, 0, 0);
        }
    }
    // epilogue
    #pragma unroll
    for (int i = 0; i < 4; ++i) {
        const int o0 = wr * 64 + i * 16 + quad * 4;
        floatx4 bz = *(const floatx4*)&bias[o0];
        #pragma unroll
        for (int j = 0; j < 4; ++j) {
            const int bnl = wc * 64 + j * 16 + m16;
            const size_t bn = (size_t)b * 4096 + n0 + bnl;
            floatx4 v = acc[i][j];
            float s[4];
            #pragma unroll
            for (int e = 0; e < 4; ++e) s[e] = 1.f / (1.f + __expf(-(v[e] + bz[e])));
            if (wr == 0) {          // r -> x0T state rows: bf16(r*hx)
                floatx4 hv = *(const floatx4*)&hx[bn * 64 + o0];
                #pragma unroll
                for (int e = 0; e < 4; ++e)
                    x0Tw[(size_t)((o0 + e + 2) * 64 + b) * 4096 + (n0 + bnl)] = f2b(s[e] * hv[e]);
            } else {                // u -> u_t[bn][o-64]
                u16x4 pk;
                #pragma unroll
                for (int e = 0; e < 4; ++e) pk[e] = f2b(s[e]);
                *(u16x4*)&u_t[bn * 64 + (o0 - 64)] = pk;
            }
        }
    }
}

// --------------------------------------- proj g: MFMA GEMM + tanh + GRU output
__global__ __launch_bounds__(256, 2) void proj_g_kernel(
        const u16* __restrict__ x0T, const u16* __restrict__ y1T,
        const u16* __restrict__ y2T, const u16* __restrict__ y3T,
        const u16* __restrict__ y4T,
        const u16* __restrict__ WT, const float* __restrict__ bias,
        const float* __restrict__ hx, const u16* __restrict__ u_t,
        float* __restrict__ out) {
    __shared__ __align__(16) u32 Xs[32 * 132];
    __shared__ __align__(16) u16 Ws[64 * 72];
    const int t = threadIdx.x;
    const int lane = t & 63, wave = t >> 6;
    const int m16 = lane & 15, quad = lane >> 4;
    const int wr = wave >> 1, wc = wave & 1;
    const int n0 = blockIdx.x * 128, b = blockIdx.y;

    const int kp = t >> 3, sgx = t & 7;
    const int wrow = t >> 2, wq = t & 3;

    floatx4 acc[2][4];
    #pragma unroll
    for (int i = 0; i < 2; ++i)
        #pragma unroll
        for (int j = 0; j < 4; ++j) acc[i][j] = (floatx4)0.f;

    for (int ki = 0; ki < 6; ++ki) {
        const int k0 = ki * 64;
        const u16* pa = xrow(k0 + 2 * kp,     b, x0T, y1T, y2T, y3T, y4T) + n0 + sgx * 16;
        const u16* pb = xrow(k0 + 2 * kp + 1, b, x0T, y1T, y2T, y3T, y4T) + n0 + sgx * 16;
        uint4 a0 = *(const uint4*)pa;
        uint4 a1 = *(const uint4*)(pa + 8);
        uint4 b0 = *(const uint4*)pb;
        uint4 b1 = *(const uint4*)(pb + 8);
        const u16* wsrc = WT + (size_t)wrow * 384 + k0 + wq * 16;
        uint4 w0 = *(const uint4*)wsrc;
        uint4 w1 = *(const uint4*)(wsrc + 8);

        u32 w[16];
        ilv(a0, b0, w);
        ilv(a1, b1, w + 8);
        __syncthreads();
        u32* xdst = &Xs[kp * 132 + sgx * 16];
        #pragma unroll
        for (int q = 0; q < 4; ++q) *(uint4*)(xdst + q * 4) = *(uint4*)(w + q * 4);
        *(uint4*)&Ws[wrow * 72 + wq * 16] = w0;
        *(uint4*)&Ws[wrow * 72 + wq * 16 + 8] = w1;
        __syncthreads();

        #pragma unroll
        for (int ks = 0; ks < 2; ++ks) {
            short8 af[2], bf[4];
            #pragma unroll
            for (int i = 0; i < 2; ++i)
                af[i] = *(const short8*)&Ws[(wr * 32 + i * 16 + m16) * 72 + ks * 32 + quad * 8];
            #pragma unroll
            for (int j = 0; j < 4; ++j) {
                const u32* xp = &Xs[(ks * 16 + quad * 4) * 132 + wc * 64 + j * 16 + m16];
                union { uint4 u; short8 s; } fu;
                fu.u.x = xp[0]; fu.u.y = xp[132]; fu.u.z = xp[264]; fu.u.w = xp[396];
                bf[j] = fu.s;
            }
            #pragma unroll
            for (int i = 0; i < 2; ++i)
                #pragma unroll
                for (int j = 0; j < 4; ++j)
                    acc[i][j] = __builtin_amdgcn_mfma_f32_16x16x32_bf16(af[i], bf[j], acc[i][j], 0, 0, 0);
        }
    }
    #pragma unroll
    for (int i = 0; i < 2; ++i) {
        const int o0 = wr * 32 + i * 16 + quad * 4;
        floatx4 bz = *(const floatx4*)&bias[o0];
        #pragma unroll
        for (int j = 0; j < 4; ++j) {
            const int bnl = wc * 64 + j * 16 + m16;
            const size_t bn = (size_t)b * 4096 + n0 + bnl;
            floatx4 v = acc[i][j];
            u16x4 uu = *(const u16x4*)&u_t[bn * 64 + o0];
            floatx4 hv = *(const floatx4*)&hx[bn * 64 + o0];
            floatx4 ov;
            #pragma unroll
            for (int e = 0; e < 4; ++e) {
                float c = tanhf(v[e] + bz[e]);
                float u = b2f(uu[e]);
                ov[e] = u * hv[e] + (1.f - u) * c;
            }
            *(floatx4*)&out[bn * 64 + o0] = ov;
        }
    }
}

// --------------------------------------------------------------------- launch
extern "C" void kernel_launch(void* const* d_in, const int* in_sizes, int n_in,
                              void* d_out, int out_size, void* d_ws, size_t ws_size,
                              hipStream_t stream) {
    (void)in_sizes; (void)n_in; (void)out_size; (void)ws_size;
    const float* inputs   = (const float*)d_in[0];
    const float* hx       = (const float*)d_in[1];
    const float* supports = (const float*)d_in[2];
    const float* w_fn     = (const float*)d_in[3];
    const float* b_fn     = (const float*)d_in[4];
    const float* w_g      = (const float*)d_in[5];
    const float* b_g      = (const float*)d_in[6];
    float* out = (float*)d_out;

    const size_t NN  = (size_t)4096 * 4096;
    const size_t XTP = (size_t)4352 * 4096;     // padded to 17 col-tiles of 256
    u16* Sb  = (u16*)d_ws;                      // 67.1 MB
    u16* x0T = Sb + 2 * NN;                     // 35.7 MB each (padded)
    u16* y1T = x0T + XTP;
    u16* y2T = y1T + XTP;
    u16* y3T = y2T + XTP;
    u16* y4T = y3T + XTP;
    u16* u_t = y4T + XTP;                       // [bn][o'] bf16, 33.6 MB
    u16* WT_fn = u_t + (size_t)262144 * 64;     // 128*384 u16
    u16* WT_g  = WT_fn + 128 * 384;             // 64*384 u16
    u16* S0b = Sb;
    u16* S1b = Sb + NN;

    const dim3 g1(16, 17, 1);                   // single GEMM
    const dim3 g2(16, 17, 2);                   // fused pair (shared B)

    cvt_bf16_kernel<<<32768, 256, 0, stream>>>(supports, Sb);
    build_x0_inputs<<<128, 256, 0, stream>>>(inputs, x0T);
    build_x0_state<<<dim3(64, 64), 256, 0, stream>>>(hx, x0T);
    wt_prep<<<192, 256, 0, stream>>>(w_fn, WT_fn, 128);
    wt_prep<<<96, 256, 0, stream>>>(w_g, WT_g, 64);
    // gconv fn diffusion: y1 = S0@x0; {y2 = 2*S0@y1 - x0, y3 = S1@y1}; y4 = 2*S1@y3 - y1
    gemm256_kernel<<<g1, 512, 0, stream>>>(S0b, nullptr, x0T, y1T, nullptr, nullptr, nullptr);
    gemm256_kernel<<<g2, 512, 0, stream>>>(S0b, S1b, y1T, y2T, y3T, x0T, nullptr);
    gemm256_kernel<<<g1, 512, 0, stream>>>(S1b, nullptr, y3T, y4T, nullptr, y1T, nullptr);
    // r,u gates (MFMA): r*hx into x0T state rows, u into u_t
    proj_fn_kernel<<<dim3(32, 64), 256, 0, stream>>>(x0T, y1T, y2T, y3T, y4T,
                                                     WT_fn, b_fn, hx, u_t, x0T);
    // gconv g diffusion
    gemm256_kernel<<<g1, 512, 0, stream>>>(S0b, nullptr, x0T, y1T, nullptr, nullptr, nullptr);
    gemm256_kernel<<<g2, 512, 0, stream>>>(S0b, S1b, y1T, y2T, y3T, x0T, nullptr);
    gemm256_kernel<<<g1, 512, 0, stream>>>(S1b, nullptr, y3T, y4T, nullptr, y1T, nullptr);
    // c = tanh(...), out = u*hx + (1-u)*c
    proj_g_kernel<<<dim3(32, 64), 256, 0, stream>>>(x0T, y1T, y2T, y3T, y4T,
                                                    WT_g, b_g, hx, u_t, out);
}